// Round 1
// 213.607 us; speedup vs baseline: 1.0133x; 1.0133x over previous
//
#include <hip/hip_runtime.h>

// Q = L @ L^T for 3x3 lower-triangular L packed as 6 floats per item:
// packed (row,col) = (0,0),(1,0),(1,1),(2,0),(2,1),(2,2) -> a,b,c,d,e,f
// Uniques: u0=a*a u1=a*b u2=a*d u3=b*b+c*c u4=b*d+c*e u5=d*d+e*e+f*f
// Row-major out[0..8] = [u0,u1,u2, u1,u3,u4, u2,u4,u5]
//
// R4 theory: dur_us = harness reset (~130us: 91us 576MiB fill + restore) +
// kernel. Traffic floor 251.7MB -> ~40us kernel @6.6TB/s. The R3 kernel's
// only non-BW costs were the per-lane 9-way switch (wave serializes 9
// exec-masked cases x 9 store iters) and ~5-way LDS conflicts on the
// compute-phase reads. This version stages the OUTPUT STREAM in LDS:
//   phase1: global->s_in, contiguous f4 lanes (coalesced)
//   phase2: item t & t+256 per thread; static stride-9 word writes to s_out
//           (9 coprime 32 -> 2 lanes/bank = free); reads stride-6 (4-way,
//           1.58x, tiny vs BW budget); NO divergence, NO runtime select.
//   phase3: s_out -> global, contiguous f4 lanes (coalesced, nontemporal)
// LDS 30KB -> 5 blocks/CU = 20 waves/CU.
// Prediction: kernel ~40-45us; if dur_us unchanged, reset dominates and we
// are at the harness floor (declare roofline).

#define THREADS 256
#define IPB 512  // items per block: s_in 12KB + s_out 18KB = 30KB

typedef float f4 __attribute__((ext_vector_type(4)));

__global__ __launch_bounds__(THREADS) void chol_to_cov_kernel(
    const float* __restrict__ in, float* __restrict__ out, long long n_items) {
  __shared__ __attribute__((aligned(16))) float s_in[IPB * 6];   // 12 KB
  __shared__ __attribute__((aligned(16))) float s_out[IPB * 9];  // 18 KB

  const int tid = threadIdx.x;
  const long long block_base = (long long)blockIdx.x * IPB;

  if (block_base + IPB <= n_items) {
    // ---- phase 1: global -> LDS, 3 float4/thread, unit lane stride ----
    const f4* __restrict__ in4 = (const f4*)(in + block_base * 6);
    f4* s4i = (f4*)s_in;
#pragma unroll
    for (int k = 0; k < 3; k++) {
      const int idx = tid + k * THREADS;  // < 768
      s4i[idx] = __builtin_nontemporal_load(&in4[idx]);
    }
    __syncthreads();

    // ---- phase 2: compute, fully static addressing, no divergence ----
#pragma unroll
    for (int t = 0; t < 2; t++) {
      const int item = tid + t * THREADS;  // < 512
      const float* p = s_in + item * 6;    // stride-6 words: 4-way, 1.58x
      const float a = p[0], b = p[1], c = p[2];
      const float d = p[3], e0 = p[4], f = p[5];
      const float u1 = a * b;
      const float u2 = a * d;
      const float u4 = b * d + c * e0;
      float* q = s_out + item * 9;  // stride-9 words: 2 lanes/bank = free
      q[0] = a * a;
      q[1] = u1;
      q[2] = u2;
      q[3] = u1;
      q[4] = b * b + c * c;
      q[5] = u4;
      q[6] = u2;
      q[7] = u4;
      q[8] = d * d + e0 * e0 + f * f;
    }
    __syncthreads();

    // ---- phase 3: LDS -> global, contiguous float4 lanes, nontemporal ----
    f4* __restrict__ out4 = (f4*)(out + block_base * 9);
    const f4* s4o = (const f4*)s_out;
#pragma unroll
    for (int k = 0; k < 4; k++) {
      const int idx = tid + k * THREADS;  // < 1024
      __builtin_nontemporal_store(s4o[idx], &out4[idx]);
    }
    const int idx4 = tid + 4 * THREADS;  // remaining 128 float4
    if (idx4 < (IPB * 9) / 4) {          // wave-uniform per wave (tid<128)
      __builtin_nontemporal_store(s4o[idx4], &out4[idx4]);
    }
  } else {
    // ---- guarded tail path (unused at 4096*1024 items) ----
    for (long long it = block_base + tid; it < n_items; it += THREADS) {
      const float a = in[it * 6 + 0];
      const float b = in[it * 6 + 1];
      const float c = in[it * 6 + 2];
      const float d = in[it * 6 + 3];
      const float e = in[it * 6 + 4];
      const float f = in[it * 6 + 5];
      float* o = out + it * 9;
      o[0] = a * a;
      o[1] = a * b;
      o[2] = a * d;
      o[3] = a * b;
      o[4] = b * b + c * c;
      o[5] = b * d + c * e;
      o[6] = a * d;
      o[7] = b * d + c * e;
      o[8] = d * d + e * e + f * f;
    }
  }
}

extern "C" void kernel_launch(void* const* d_in, const int* in_sizes, int n_in,
                              void* d_out, int out_size, void* d_ws,
                              size_t ws_size, hipStream_t stream) {
  const float* in = (const float*)d_in[0];
  float* out = (float*)d_out;
  const long long n_items = (long long)in_sizes[0] / 6;  // 4,194,304
  const long long grid = (n_items + IPB - 1) / IPB;      // 8192
  chol_to_cov_kernel<<<(int)grid, THREADS, 0, stream>>>(in, out, n_items);
}